// Round 4
// baseline (774.552 us; speedup 1.0000x reference)
//
#include <hip/hip_runtime.h>
#include <hip/hip_bf16.h>
#include <stdint.h>

// ---------------------------------------------------------------------------
// TtAttention: x->(Q,K,V) proj -> RoPE -> causal GQA flash attention -> out proj
// B=4 S=1024 D=4096 NH=32 NKV=8 HD=128, window 4096 >= S => pure causal.
// Round 7: big GEMM re-tiled 128x256 (grid 512 -> 2 blocks/CU, 4 waves/SIMD)
// with 3-deep circular LDS (72 KB), ONE fused counted vmcnt(3)+s_barrier per
// K-tile (R2-style coarse schedule -- R3's fine phases regressed), per-wave
// 64x64 output. T2 source-side swizzle kept (0 bank conflicts). Attention
// (R5) and K/V-proj (128^2) unchanged.
// ---------------------------------------------------------------------------

typedef __bf16 bf16x8 __attribute__((ext_vector_type(8)));
typedef float floatx4 __attribute__((ext_vector_type(4)));

__device__ __forceinline__ unsigned short f2bf(float f) {
    union { float f; uint32_t u; } v; v.f = f;
    uint32_t u = v.u;
    uint32_t r = (u + 0x7FFFu + ((u >> 16) & 1u)) >> 16;   // RNE
    return (unsigned short)r;
}
__device__ __forceinline__ float bf2f(unsigned short h) {
    union { uint32_t u; float f; } v; v.u = ((uint32_t)h) << 16;
    return v.f;
}

// async global->LDS, 16 bytes per lane; lds dest is wave-uniform base,
// HW places lane i's data at base + i*16 (m97/m104 semantics).
__device__ __forceinline__ void async_copy16(const void* g, void* l) {
    __builtin_amdgcn_global_load_lds(
        (const __attribute__((address_space(1))) unsigned int*)g,
        (__attribute__((address_space(3))) unsigned int*)l,
        16, 0, 0);
}

// ---------------- cast fp32 -> bf16, 4 elems / thread ----------------------
__global__ void cast_bf16_kernel(const float* __restrict__ in,
                                 unsigned short* __restrict__ out, int n4) {
    int i = blockIdx.x * blockDim.x + threadIdx.x;
    if (i >= n4) return;
    float4 v = ((const float4*)in)[i];
    ushort4 o;
    o.x = f2bf(v.x); o.y = f2bf(v.y); o.z = f2bf(v.z); o.w = f2bf(v.w);
    ((ushort4*)out)[i] = o;
}

// ---------------- GEMM 128x128 (kept for K/V proj): C = A * B^T ------------
#define GBM 128
#define GBN 128
#define GBK 64

__global__ __launch_bounds__(256)
void gemm_bt_kernel(const unsigned short* __restrict__ A,
                    const unsigned short* __restrict__ B,
                    void* __restrict__ Cout, int M, int N, int K, int out_is_bf16)
{
    __shared__ unsigned short As[GBM * GBK];   // 16 KB swizzled
    __shared__ unsigned short Bs[GBN * GBK];   // 16 KB

    const int tid  = threadIdx.x;
    const int lane = tid & 63;
    const int wave = tid >> 6;
    const int quad = lane >> 4;
    const int l15  = lane & 15;

    const int bm = blockIdx.y * GBM;
    const int bn = blockIdx.x * GBN;
    const int waveM = (wave >> 1) * 64;
    const int waveN = (wave & 1) * 64;

    floatx4 acc[4][4];
    #pragma unroll
    for (int i = 0; i < 4; i++)
        #pragma unroll
        for (int j = 0; j < 4; j++)
            acc[i][j] = floatx4{0.f, 0.f, 0.f, 0.f};

    const int srow = wave * 8 + (lane >> 3);          // + i*32
    const int gcol = (((lane & 7) ^ (lane >> 3)) << 4);  // byte offset in row
    uint8_t* AsB = (uint8_t*)As;
    uint8_t* BsB = (uint8_t*)Bs;

    for (int k0 = 0; k0 < K; k0 += GBK) {
        __syncthreads();   // prior iter frag reads complete before re-staging
        const uint8_t* Ab = (const uint8_t*)A + (size_t)k0 * 2;
        const uint8_t* Bb = (const uint8_t*)B + (size_t)k0 * 2;
        #pragma unroll
        for (int i = 0; i < 4; i++) {
            int row = i * 32 + srow;
            async_copy16(Ab + (size_t)(bm + row) * K * 2 + gcol, AsB + i * 4096 + wave * 1024);
            async_copy16(Bb + (size_t)(bn + row) * K * 2 + gcol, BsB + i * 4096 + wave * 1024);
        }
        __syncthreads();   // drains vmcnt before barrier

        #pragma unroll
        for (int kk = 0; kk < 2; kk++) {
            bf16x8 af[4], bfr[4];
            #pragma unroll
            for (int i = 0; i < 4; i++) {
                int row = waveM + i * 16 + l15;
                af[i] = *(const bf16x8*)(AsB + row * 128 +
                          ((((kk << 2) | quad) ^ (l15 & 7)) << 4));
            }
            #pragma unroll
            for (int j = 0; j < 4; j++) {
                int row = waveN + j * 16 + l15;
                bfr[j] = *(const bf16x8*)(BsB + row * 128 +
                          ((((kk << 2) | quad) ^ (l15 & 7)) << 4));
            }
            #pragma unroll
            for (int i = 0; i < 4; i++)
                #pragma unroll
                for (int j = 0; j < 4; j++)
                    acc[i][j] = __builtin_amdgcn_mfma_f32_16x16x32_bf16(af[i], bfr[j], acc[i][j], 0, 0, 0);
        }
    }

    const int rowBase = bm + waveM + quad * 4;
    const int colBase = bn + waveN + l15;
    if (out_is_bf16) {
        unsigned short* C = (unsigned short*)Cout;
        #pragma unroll
        for (int i = 0; i < 4; i++)
            #pragma unroll
            for (int j = 0; j < 4; j++)
                #pragma unroll
                for (int r = 0; r < 4; r++)
                    C[(size_t)(rowBase + i * 16 + r) * N + colBase + j * 16] = f2bf(acc[i][j][r]);
    } else {
        float* C = (float*)Cout;
        #pragma unroll
        for (int i = 0; i < 4; i++)
            #pragma unroll
            for (int j = 0; j < 4; j++)
                #pragma unroll
                for (int r = 0; r < 4; r++)
                    C[(size_t)(rowBase + i * 16 + r) * N + colBase + j * 16] = acc[i][j][r];
    }
}

// ---------------- GEMM 128x256, BK=32, 3-deep circular LDS -----------------
// C[M,N] = A[M,K]*B[N,K]^T. 512 thr = 8 waves (2Mx4N); per-wave 64x64 out.
// LDS: 3 slots x (A 8KB + B 16KB) = 72 KB -> 2 blocks/CU (grid 512 = 2/CU,
// 4 waves/SIMD: TLP hides read/stage windows). Per tile: ONE fused
// "s_waitcnt vmcnt(3); s_barrier" (counted: tile t+1's 3 loads stay in
// flight), stage(t+2) post-barrier, 8 ds_read + 16 MFMA compiler-scheduled.
// Swizzle: PHYS(r,g16) = r*64 + ((g ^ ((r>>1)&3))<<4), realized by permuting
// the per-lane GLOBAL source granule (both-sides rule, m104/m231).
#define WBM 128
#define WBN 256
#define WSLOT 24576

__global__ __launch_bounds__(512, 4)
void gemm_bt_256_kernel(const unsigned short* __restrict__ A,
                        const unsigned short* __restrict__ B,
                        void* __restrict__ Cout, int M, int N, int K, int out_is_bf16)
{
    __shared__ uint8_t lds[3 * WSLOT];   // 72 KB

    const int tid  = threadIdx.x;
    const int lane = tid & 63;
    const int wave = tid >> 6;     // 0..7
    const int quad = lane >> 4;
    const int l15  = lane & 15;
    const int wr   = wave >> 2;    // 0..1 -> C rows wr*64..+64
    const int wc   = wave & 3;     // 0..3 -> C cols wc*64..+64

    // XCD-aware bijective swizzle (grid 16x32 = 512, 512 % 8 == 0)
    const int nwg = gridDim.x * gridDim.y;
    int orig = blockIdx.y * gridDim.x + blockIdx.x;
    int swzb = (nwg & 7) ? orig : ((orig & 7) * (nwg >> 3) + (orig >> 3));
    const int bm = (swzb / gridDim.x) * WBM;
    const int bn = (swzb % gridDim.x) * WBN;

    // staging: A 1 inst/wave (rows wave*16 + lane>>2), B 2 insts/wave
    // (rows wave*32 + lane>>2, +16). source granule = (lane&3)^((lane>>3)&3)
    // realizes PHYS with linear LDS dest (s(r) = (r>>1)&3 = (lane>>3)&3).
    const int sgr = lane >> 2;
    const int sg  = (((lane & 3) ^ ((lane >> 3) & 3)) << 4);
    const uint8_t* Ag  = (const uint8_t*)(A + (size_t)(bm + wave * 16 + sgr) * K) + sg;
    const uint8_t* Bg0 = (const uint8_t*)(B + (size_t)(bn + wave * 32 + sgr) * K) + sg;
    const uint8_t* Bg1 = (const uint8_t*)(B + (size_t)(bn + wave * 32 + 16 + sgr) * K) + sg;
    const int ldsA  = wave * 1024;
    const int ldsB0 = 8192 + wave * 2048;
    const int ldsB1 = ldsB0 + 1024;

    // ds_read fragment offsets: row = base16 + l15 => s(r) = (l15>>1)&3
    const int rsw  = (quad ^ ((l15 >> 1) & 3)) << 4;
    const int aoff = (wr * 64 + l15) * 64 + rsw;            // + m*1024
    const int boff = 8192 + (wc * 64 + l15) * 64 + rsw;     // + n*1024

    floatx4 acc[4][4];
    #pragma unroll
    for (int m = 0; m < 4; m++)
        #pragma unroll
        for (int n = 0; n < 4; n++)
            acc[m][n] = floatx4{0.f, 0.f, 0.f, 0.f};

    auto stage = [&](int t, uint8_t* buf) {
        const size_t koff = (size_t)t * 64;   // t*32 bf16 * 2B
        async_copy16(Ag  + koff, buf + ldsA);
        async_copy16(Bg0 + koff, buf + ldsB0);
        async_copy16(Bg1 + koff, buf + ldsB1);
    };

    const int NT = K >> 5;          // K % 32 == 0 (K = 4096 here)
    stage(0, lds);
    if (NT > 1) stage(1, lds + WSLOT);

    int cur = 0;
    for (int t = 0; t < NT; ++t) {
        // certify tile t (retire its 3 loads); keep tile t+1's 3 in flight.
        if (t + 1 < NT)
            asm volatile("s_waitcnt vmcnt(3)\n\ts_barrier" ::: "memory");
        else
            asm volatile("s_waitcnt vmcnt(0)\n\ts_barrier" ::: "memory");

        // slot (cur+2)%3 held tile t-1, fully read before the barrier above.
        int nxt2 = cur + 2; if (nxt2 >= 3) nxt2 -= 3;
        if (t + 2 < NT) stage(t + 2, lds + nxt2 * WSLOT);

        const uint8_t* buf = lds + cur * WSLOT;
        bf16x8 a[4], b[4];
        #pragma unroll
        for (int m = 0; m < 4; m++) a[m] = *(const bf16x8*)(buf + aoff + m * 1024);
        #pragma unroll
        for (int n = 0; n < 4; n++) b[n] = *(const bf16x8*)(buf + boff + n * 1024);
        __builtin_amdgcn_s_setprio(1);
        #pragma unroll
        for (int m = 0; m < 4; m++)
            #pragma unroll
            for (int n = 0; n < 4; n++)
                acc[m][n] = __builtin_amdgcn_mfma_f32_16x16x32_bf16(a[m], b[n], acc[m][n], 0, 0, 0);
        __builtin_amdgcn_s_setprio(0);

        cur = (cur == 2) ? 0 : cur + 1;
    }

    // epilogue: D row = quad*4 + reg (A side), col = l15 (B side) — m89/m91
    const int rowBase = bm + wr * 64 + quad * 4;
    const int colBase = bn + wc * 64 + l15;
    if (out_is_bf16) {
        unsigned short* C = (unsigned short*)Cout;
        #pragma unroll
        for (int i = 0; i < 4; i++)
            #pragma unroll
            for (int j = 0; j < 4; j++)
                #pragma unroll
                for (int r = 0; r < 4; r++)
                    C[(size_t)(rowBase + i * 16 + r) * N + colBase + j * 16] = f2bf(acc[i][j][r]);
    } else {
        float* C = (float*)Cout;
        #pragma unroll
        for (int i = 0; i < 4; i++)
            #pragma unroll
            for (int j = 0; j < 4; j++)
                #pragma unroll
                for (int r = 0; r < 4; r++)
                    C[(size_t)(rowBase + i * 16 + r) * N + colBase + j * 16] = acc[i][j][r];
    }
}

// ---------------- RoPE in-place on bf16 [*, nh, 128] -----------------------
__global__ void rope_kernel(unsigned short* __restrict__ t,
                            const float* __restrict__ fc,
                            const float* __restrict__ fs,
                            int nh, int total_pairs) {
    int idx = blockIdx.x * blockDim.x + threadIdx.x;
    if (idx >= total_pairs) return;
    int j   = idx & 63;            // HD/2 = 64
    int tmp = idx >> 6;            // (b*S + s)*nh + h
    int s   = (tmp / nh) & 1023;   // S = 1024
    float c  = fc[s * 64 + j];
    float sn = fs[s * 64 + j];
    size_t base = (size_t)tmp * 128 + j * 2;
    float tr = bf2f(t[base]), ti = bf2f(t[base + 1]);
    t[base]     = f2bf(tr * c - ti * sn);
    t[base + 1] = f2bf(tr * sn + ti * c);
}

// ---------------- flash attention (causal, GQA rep=4) ----------------------
// 512 thr / 8 waves; block owns 128 q-rows (wave w: rows q0+w*16..+15).
// Async double-buffered K/V staging (counted vmcnt(4)), T2 source-side
// swizzle, per-wave causal tile skip, setprio around MFMA clusters.
#define AS_  1024
#define AHD 128
#define ANH 32
#define ANKV 8

__global__ __launch_bounds__(512, 4)
void attn_kernel(const unsigned short* __restrict__ Q,   // [B,S,NH,HD] bf16
                 const unsigned short* __restrict__ Kk,  // [B,S,NKV,HD]
                 const unsigned short* __restrict__ Vt,  // [NKV*HD][B*S]  (pre-transposed)
                 unsigned short* __restrict__ O)         // [B,S,NH,HD]
{
    __shared__ uint8_t lds[81920];   // [0,32K) K dbuf, [32K,64K) V dbuf, [64K,80K) P

    const int tid  = threadIdx.x;
    const int lane = tid & 63;
    const int wave = tid >> 6;      // 0..7
    const int quad = lane >> 4;
    const int l15  = lane & 15;

    const int bid = blockIdx.x;
    const int qt2 = 7 - (bid & 7);     // heavy q-tiles first
    const int h   = (bid >> 3) & 31;
    const int b   = bid >> 8;
    const int hk  = h >> 2;            // rep = NH/NKV = 4
    const int q0  = qt2 * 128;

    uint8_t* ldsK = lds;
    uint8_t* ldsV = lds + 32768;
    uint8_t* Ps   = lds + 65536 + wave * 2048;   // per-wave [16][64] swizzled

    const int krow0 = (2 * wave + 0) * 4 + (lane >> 4);
    const int krow1 = (2 * wave + 1) * 4 + (lane >> 4);
    const int kg0 = ((lane & 15) ^ (0 + (lane >> 4))) * 8;   // elem offset in row
    const int kg1 = ((lane & 15) ^ (4 + (lane >> 4))) * 8;
    const unsigned short* Kg0 = Kk + ((size_t)(b * AS_ + krow0) * ANKV + hk) * AHD + kg0;
    const unsigned short* Kg1 = Kk + ((size_t)(b * AS_ + krow1) * ANKV + hk) * AHD + kg1;
    const int vrow0 = (2 * wave + 0) * 8 + (lane >> 3);
    const int vrow1 = (2 * wave + 1) * 8 + (lane >> 3);
    const int vg = ((lane & 7) ^ (lane >> 3)) * 8;
    const unsigned short* Vg0 = Vt + (size_t)(hk * AHD + vrow0) * (4 * AS_) + b * AS_ + vg;
    const unsigned short* Vg1 = Vt + (size_t)(hk * AHD + vrow1) * (4 * AS_) + b * AS_ + vg;

    auto stage = [&](int t) {
        uint8_t* kb_ = ldsK + (t & 1) * 16384;
        uint8_t* vb_ = ldsV + (t & 1) * 16384;
        async_copy16(Kg0 + (size_t)t * 65536, kb_ + (2 * wave + 0) * 1024);
        async_copy16(Kg1 + (size_t)t * 65536, kb_ + (2 * wave + 1) * 1024);
        async_copy16(Vg0 + t * 64, vb_ + (2 * wave + 0) * 1024);
        async_copy16(Vg1 + t * 64, vb_ + (2 * wave + 1) * 1024);
    };

    bf16x8 aq[4];
    {
        const int qrow = q0 + wave * 16 + l15;
        const unsigned short* src = Q + ((size_t)(b * AS_ + qrow) * ANH + h) * AHD;
        #pragma unroll
        for (int kk = 0; kk < 4; kk++)
            aq[kk] = *(const bf16x8*)(src + kk * 32 + quad * 8);
    }

    float lsum[4];
    #pragma unroll
    for (int r = 0; r < 4; r++) lsum[r] = 0.0f;
    floatx4 o[8];
    #pragma unroll
    for (int d = 0; d < 8; d++) o[d] = floatx4{0.f, 0.f, 0.f, 0.f};

    const float scale = 0.08838834764831845f;  // 1/sqrt(128)
    const int wMaxKt = (q0 + wave * 16 + 15) >> 6;  // last tile this wave needs
    const int ktMax  = (q0 + 127) >> 6;             // = 2*qt2 + 1

    stage(0);
    const int swz = (l15 & 7) << 4;   // read-side XOR swizzle term

    for (int kt = 0; kt <= ktMax; ++kt) {
        if (kt < ktMax) {
            stage(kt + 1);   // safe: trailing barrier of iter kt-1 passed
            asm volatile("s_waitcnt vmcnt(4)\n\ts_barrier" ::: "memory");
        } else {
            asm volatile("s_waitcnt vmcnt(0)\n\ts_barrier" ::: "memory");
        }

        if (kt <= wMaxKt) {
            const uint8_t* kb_ = ldsK + (kt & 1) * 16384;
            const uint8_t* vb_ = ldsV + (kt & 1) * 16384;

            floatx4 sc[4];
            #pragma unroll
            for (int j = 0; j < 4; j++) sc[j] = floatx4{0.f, 0.f, 0.f, 0.f};
            __builtin_amdgcn_s_setprio(1);
            #pragma unroll
            for (int j = 0; j < 4; j++)
                #pragma unroll
                for (int kk = 0; kk < 4; kk++) {
                    bf16x8 bk = *(const bf16x8*)(kb_ + (j * 16 + l15) * 256 +
                                  (((kk * 4 + quad) << 4) ^ swz));
                    sc[j] = __builtin_amdgcn_mfma_f32_16x16x32_bf16(aq[kk], bk, sc[j], 0, 0, 0);
                }
            __builtin_amdgcn_s_setprio(0);

            #pragma unroll
            for (int r = 0; r < 4; r++) {
                const int row  = quad * 4 + r;
                const int qrow = q0 + wave * 16 + row;
                const bool needMask = (kt * 64 + 63 > qrow);
                float acc = 0.0f;
                #pragma unroll
                for (int j = 0; j < 4; j++) {
                    float e = __expf(sc[j][r] * scale);
                    if (needMask) {
                        int key = kt * 64 + j * 16 + l15;
                        if (key > qrow) e = 0.0f;   // causal
                    }
                    acc += e;
                    int g = (j * 2 + (l15 >> 3)) ^ (row & 7);
                    *(unsigned short*)(Ps + row * 128 + (g << 4) + (l15 & 7) * 2) = f2bf(e);
                }
                lsum[r] += acc;
            }

            __builtin_amdgcn_s_setprio(1);
            #pragma unroll
            for (int kk = 0; kk < 2; kk++) {
                bf16x8 ap = *(const bf16x8*)(Ps + l15 * 128 +
                              (((kk * 4 + quad) << 4) ^ swz));
                #pragma unroll
                for (int d = 0; d < 8; d++) {
                    bf16x8 bv = *(const bf16x8*)(vb_ + (d * 16 + l15) * 128 +
                                  (((kk * 4 + quad) << 4) ^ swz));
                    o[d] = __builtin_amdgcn_mfma_f32_16x16x32_bf16(ap, bv, o[d], 0, 0, 0);
                }
            }
            __builtin_amdgcn_s_setprio(0);
        }

        asm volatile("s_barrier" ::: "memory");
    }

    #pragma unroll
    for (int r = 0; r < 4; r++) {
        float s = lsum[r];
        #pragma unroll
        for (int off = 1; off < 16; off <<= 1)
            s += __shfl_xor(s, off, 64);
        float inv = 1.0f / s;
        int qrow = q0 + wave * 16 + quad * 4 + r;
        unsigned short* dst = O + ((size_t)(b * AS_ + qrow) * ANH + h) * AHD;
        #pragma unroll
        for (int d = 0; d < 8; d++)
            dst[d * 16 + l15] = f2bf(o[d][r] * inv);
    }
}

// ---------------------------------------------------------------------------
extern "C" void kernel_launch(void* const* d_in, const int* in_sizes, int n_in,
                              void* d_out, int out_size, void* d_ws, size_t ws_size,
                              hipStream_t stream)
{
    const float* x  = (const float*)d_in[0];
    const float* wq = (const float*)d_in[1];
    const float* wk = (const float*)d_in[2];
    const float* wv = (const float*)d_in[3];
    const float* wo = (const float*)d_in[4];
    const float* fc = (const float*)d_in[5];
    const float* fs = (const float*)d_in[6];

    const int B = 4, S = 1024, D = 4096, NH = 32, NKV = 8, HD = 128;
    const int M    = B * S;       // 4096 tokens
    const int NQ   = NH * HD;     // 4096
    const int NKVD = NKV * HD;    // 1024

    unsigned short* ws = (unsigned short*)d_ws;
    size_t off = 0;
    unsigned short* xb  = ws + off; off += (size_t)M * D;      // 32 MiB
    unsigned short* wqb = ws + off; off += (size_t)NQ * D;     // 32 MiB
    unsigned short* wkb = ws + off; off += (size_t)NKVD * D;   //  8 MiB
    unsigned short* wvb = ws + off; off += (size_t)NKVD * D;   //  8 MiB
    unsigned short* wob = ws + off; off += (size_t)D * NQ;     // 32 MiB
    unsigned short* qb  = ws + off; off += (size_t)M * NQ;     // 32 MiB
    unsigned short* kb  = ws + off; off += (size_t)M * NKVD;   //  8 MiB
    unsigned short* vtb = ws + off; off += (size_t)NKVD * M;   //  8 MiB (V^T)
    unsigned short* aob = ws + off; off += (size_t)M * NQ;     // 32 MiB

    // 1) casts fp32 -> bf16
    {
        struct { const float* src; unsigned short* dst; size_t n; } jobs[5] = {
            { x,  xb,  (size_t)M * D },
            { wq, wqb, (size_t)NQ * D },
            { wk, wkb, (size_t)NKVD * D },
            { wv, wvb, (size_t)NKVD * D },
            { wo, wob, (size_t)D * NQ },
        };
        for (int i = 0; i < 5; i++) {
            int n4 = (int)(jobs[i].n / 4);
            cast_bf16_kernel<<<(n4 + 255) / 256, 256, 0, stream>>>(jobs[i].src, jobs[i].dst, n4);
        }
    }

    // 2) projections. Q-proj on 128x256 kernel (grid 16x32 = 512 = 2/CU).
    gemm_bt_256_kernel<<<dim3(NQ / WBN, M / WBM), 512, 0, stream>>>(xb,  wqb, qb,  M,   NQ, D, 1);
    gemm_bt_kernel<<<dim3(NKVD / GBN, M / GBM), 256, 0, stream>>>(xb,  wkb, kb,  M, NKVD, D, 1);
    gemm_bt_kernel<<<dim3(M / GBN, NKVD / GBM), 256, 0, stream>>>(wvb, xb,  vtb, NKVD, M, D, 1);

    // 3) RoPE in-place on Q and K (not V)
    {
        int pq = M * NH * (HD / 2);
        rope_kernel<<<(pq + 255) / 256, 256, 0, stream>>>(qb, fc, fs, NH, pq);
        int pk = M * NKV * (HD / 2);
        rope_kernel<<<(pk + 255) / 256, 256, 0, stream>>>(kb, fc, fs, NKV, pk);
    }

    // 4) flash attention -> aob (bf16): 128 q-rows per block, 512 threads
    attn_kernel<<<B * NH * (S / 128), 512, 0, stream>>>(qb, kb, vtb, aob);

    // 5) output projection (fp32 out to d_out)
    gemm_bt_256_kernel<<<dim3(D / WBN, M / WBM), 512, 0, stream>>>(aob, wob, d_out, M, D, NQ, 0);
}

// Round 6
// 741.822 us; speedup vs baseline: 1.0441x; 1.0441x over previous
//
#include <hip/hip_runtime.h>
#include <hip/hip_bf16.h>
#include <stdint.h>

// ---------------------------------------------------------------------------
// TtAttention: x->(Q,K,V) proj -> RoPE -> causal GQA flash attention -> out proj
// B=4 S=1024 D=4096 NH=32 NKV=8 HD=128, window 4096 >= S => pure causal.
// Round 8 (resubmit; round-5 bench was an infra container failure, audited
// clean for OOB/deadlock): big GEMM = m201-faithful 8-phase schedule on
// 256^2/BK=64/2-dbuf: 4 phases per K-tile {ds_read subtile + stage 1
// half-tile + s_barrier + lgkmcnt(0) + setprio + 16 MFMA + s_barrier}, NO
// sched_barrier (R3 lesson / m141), interleaved half-tiles staged in
// read-retirement order, counted vmcnt(6) ONCE per tile (3 half-tiles in
// flight). B0 frags held in regs p0->p3. Attention (R5) unchanged.
// ---------------------------------------------------------------------------

typedef __bf16 bf16x8 __attribute__((ext_vector_type(8)));
typedef float floatx4 __attribute__((ext_vector_type(4)));

__device__ __forceinline__ unsigned short f2bf(float f) {
    union { float f; uint32_t u; } v; v.f = f;
    uint32_t u = v.u;
    uint32_t r = (u + 0x7FFFu + ((u >> 16) & 1u)) >> 16;   // RNE
    return (unsigned short)r;
}
__device__ __forceinline__ float bf2f(unsigned short h) {
    union { uint32_t u; float f; } v; v.u = ((uint32_t)h) << 16;
    return v.f;
}

// async global->LDS, 16 bytes per lane; lds dest is wave-uniform base,
// HW places lane i's data at base + i*16 (m97/m104 semantics).
__device__ __forceinline__ void async_copy16(const void* g, void* l) {
    __builtin_amdgcn_global_load_lds(
        (const __attribute__((address_space(1))) unsigned int*)g,
        (__attribute__((address_space(3))) unsigned int*)l,
        16, 0, 0);
}

// ---------------- cast fp32 -> bf16, 4 elems / thread ----------------------
__global__ void cast_bf16_kernel(const float* __restrict__ in,
                                 unsigned short* __restrict__ out, int n4) {
    int i = blockIdx.x * blockDim.x + threadIdx.x;
    if (i >= n4) return;
    float4 v = ((const float4*)in)[i];
    ushort4 o;
    o.x = f2bf(v.x); o.y = f2bf(v.y); o.z = f2bf(v.z); o.w = f2bf(v.w);
    ((ushort4*)out)[i] = o;
}

// ---------------- GEMM 128x128 (kept for K/V proj): C = A * B^T ------------
#define GBM 128
#define GBN 128
#define GBK 64

__global__ __launch_bounds__(256)
void gemm_bt_kernel(const unsigned short* __restrict__ A,
                    const unsigned short* __restrict__ B,
                    void* __restrict__ Cout, int M, int N, int K, int out_is_bf16)
{
    __shared__ unsigned short As[GBM * GBK];   // 16 KB swizzled
    __shared__ unsigned short Bs[GBN * GBK];   // 16 KB

    const int tid  = threadIdx.x;
    const int lane = tid & 63;
    const int wave = tid >> 6;
    const int quad = lane >> 4;
    const int l15  = lane & 15;

    const int bm = blockIdx.y * GBM;
    const int bn = blockIdx.x * GBN;
    const int waveM = (wave >> 1) * 64;
    const int waveN = (wave & 1) * 64;

    floatx4 acc[4][4];
    #pragma unroll
    for (int i = 0; i < 4; i++)
        #pragma unroll
        for (int j = 0; j < 4; j++)
            acc[i][j] = floatx4{0.f, 0.f, 0.f, 0.f};

    const int srow = wave * 8 + (lane >> 3);          // + i*32
    const int gcol = (((lane & 7) ^ (lane >> 3)) << 4);  // byte offset in row
    uint8_t* AsB = (uint8_t*)As;
    uint8_t* BsB = (uint8_t*)Bs;

    for (int k0 = 0; k0 < K; k0 += GBK) {
        __syncthreads();   // prior iter frag reads complete before re-staging
        const uint8_t* Ab = (const uint8_t*)A + (size_t)k0 * 2;
        const uint8_t* Bb = (const uint8_t*)B + (size_t)k0 * 2;
        #pragma unroll
        for (int i = 0; i < 4; i++) {
            int row = i * 32 + srow;
            async_copy16(Ab + (size_t)(bm + row) * K * 2 + gcol, AsB + i * 4096 + wave * 1024);
            async_copy16(Bb + (size_t)(bn + row) * K * 2 + gcol, BsB + i * 4096 + wave * 1024);
        }
        __syncthreads();   // drains vmcnt before barrier

        #pragma unroll
        for (int kk = 0; kk < 2; kk++) {
            bf16x8 af[4], bfr[4];
            #pragma unroll
            for (int i = 0; i < 4; i++) {
                int row = waveM + i * 16 + l15;
                af[i] = *(const bf16x8*)(AsB + row * 128 +
                          ((((kk << 2) | quad) ^ (l15 & 7)) << 4));
            }
            #pragma unroll
            for (int j = 0; j < 4; j++) {
                int row = waveN + j * 16 + l15;
                bfr[j] = *(const bf16x8*)(BsB + row * 128 +
                          ((((kk << 2) | quad) ^ (l15 & 7)) << 4));
            }
            #pragma unroll
            for (int i = 0; i < 4; i++)
                #pragma unroll
                for (int j = 0; j < 4; j++)
                    acc[i][j] = __builtin_amdgcn_mfma_f32_16x16x32_bf16(af[i], bfr[j], acc[i][j], 0, 0, 0);
        }
    }

    const int rowBase = bm + waveM + quad * 4;
    const int colBase = bn + waveN + l15;
    if (out_is_bf16) {
        unsigned short* C = (unsigned short*)Cout;
        #pragma unroll
        for (int i = 0; i < 4; i++)
            #pragma unroll
            for (int j = 0; j < 4; j++)
                #pragma unroll
                for (int r = 0; r < 4; r++)
                    C[(size_t)(rowBase + i * 16 + r) * N + colBase + j * 16] = f2bf(acc[i][j][r]);
    } else {
        float* C = (float*)Cout;
        #pragma unroll
        for (int i = 0; i < 4; i++)
            #pragma unroll
            for (int j = 0; j < 4; j++)
                #pragma unroll
                for (int r = 0; r < 4; r++)
                    C[(size_t)(rowBase + i * 16 + r) * N + colBase + j * 16] = acc[i][j][r];
    }
}

// ---------------- GEMM 256x256, BK=64, 8-phase (m201 port) -----------------
// C[M,N] = A[M,K]*B[N,K]^T. 512 thr = 8 waves (2Mx4N); per-wave 128x64 out.
// LDS: 2 buffers x {A[256][64] + B[256][64]} bf16 = 128 KB.
// PHYS(r, g16) = r*128 + ((g ^ (r&7))<<4), realized on the GLOBAL source
// granule so global_load_lds dest stays linear (m104/m231 both-sides rule).
// Interleaved half-tiles (read-retirement order): A0'={rows 0-63,128-191},
// A1'={64-127,192-255}, B0'={rows%64 in [0,32)}, B1'={rows%64 in [32,64)}.
// Phase p of tile t: p0 {read A0'+B0' (12), stage A1'(t+1)}, p1 {read B1'(4),
// stage A0'(t+2)}, p2 {read A1'(8), stage B0'(t+2)}, p3 {no reads (B0' held),
// stage B1'(t+2), GATE vmcnt(6)}. Each phase: barrier, lgkmcnt(0), setprio,
// 16 MFMA (one C-quadrant x K=64), barrier.
__global__ __launch_bounds__(512, 2)
void gemm_bt_256_kernel(const unsigned short* __restrict__ A,
                        const unsigned short* __restrict__ B,
                        void* __restrict__ Cout, int M, int N, int K, int out_is_bf16)
{
    __shared__ uint8_t lds[2 * 65536];   // 128 KB

    const int tid  = threadIdx.x;
    const int lane = tid & 63;
    const int wave = tid >> 6;     // 0..7
    const int quad = lane >> 4;
    const int l15  = lane & 15;
    const int wr   = wave >> 2;    // 0..1 -> C rows wr*128..+128
    const int wc   = wave & 3;     // 0..3 -> C cols wc*64..+64

    // XCD-aware bijective swizzle (grid 16x16 = 256 % 8 == 0)
    const int nwg = gridDim.x * gridDim.y;
    int orig = blockIdx.y * gridDim.x + blockIdx.x;
    int swzb = (nwg & 7) ? orig : ((orig & 7) * (nwg >> 3) + (orig >> 3));
    const int bm = (swzb / gridDim.x) * 256;
    const int bn = (swzb % gridDim.x) * 256;

    // ---- staging geometry: each inst = 8 rows x 128B; lane l covers row
    // base+(l>>3), slot l&7; fetches global granule (l&7)^(l>>3) (realizes
    // PHYS with linear LDS dest since base rows are multiples of 8).
    const int srw = lane >> 3;
    const int sgb = (((lane & 7) ^ (lane >> 3)) << 4);
    // chunk base rows (wave-uniform):
    const int a0r0 = wave * 8,       a0r1 = 128 + wave * 8;
    const int a1r0 = 64 + wave * 8,  a1r1 = 192 + wave * 8;
    const int b0r0 = (wave >> 2) * 64 + (wave & 3) * 8;
    const int b0r1 = ((wave + 8) >> 2) * 64 + (wave & 3) * 8;
    const int b1r0 = b0r0 + 32,      b1r1 = b0r1 + 32;
    // per-thread global source pointers (+ t*128 bytes per K-tile)
    const uint8_t* pA00 = (const uint8_t*)A + (size_t)(bm + a0r0 + srw) * K * 2 + sgb;
    const uint8_t* pA01 = (const uint8_t*)A + (size_t)(bm + a0r1 + srw) * K * 2 + sgb;
    const uint8_t* pA10 = (const uint8_t*)A + (size_t)(bm + a1r0 + srw) * K * 2 + sgb;
    const uint8_t* pA11 = (const uint8_t*)A + (size_t)(bm + a1r1 + srw) * K * 2 + sgb;
    const uint8_t* pB00 = (const uint8_t*)B + (size_t)(bn + b0r0 + srw) * K * 2 + sgb;
    const uint8_t* pB01 = (const uint8_t*)B + (size_t)(bn + b0r1 + srw) * K * 2 + sgb;
    const uint8_t* pB10 = (const uint8_t*)B + (size_t)(bn + b1r0 + srw) * K * 2 + sgb;
    const uint8_t* pB11 = (const uint8_t*)B + (size_t)(bn + b1r1 + srw) * K * 2 + sgb;

    auto stA0 = [&](int t) {
        uint8_t* d = lds + (t & 1) * 65536;
        const size_t ko = (size_t)t * 128;
        async_copy16(pA00 + ko, d + a0r0 * 128);
        async_copy16(pA01 + ko, d + a0r1 * 128);
    };
    auto stA1 = [&](int t) {
        uint8_t* d = lds + (t & 1) * 65536;
        const size_t ko = (size_t)t * 128;
        async_copy16(pA10 + ko, d + a1r0 * 128);
        async_copy16(pA11 + ko, d + a1r1 * 128);
    };
    auto stB0 = [&](int t) {
        uint8_t* d = lds + (t & 1) * 65536 + 32768;
        const size_t ko = (size_t)t * 128;
        async_copy16(pB00 + ko, d + b0r0 * 128);
        async_copy16(pB01 + ko, d + b0r1 * 128);
    };
    auto stB1 = [&](int t) {
        uint8_t* d = lds + (t & 1) * 65536 + 32768;
        const size_t ko = (size_t)t * 128;
        async_copy16(pB10 + ko, d + b1r0 * 128);
        async_copy16(pB11 + ko, d + b1r1 * 128);
    };

    // ds_read offsets
    const int rs0 = ((0 + quad) ^ (l15 & 7)) << 4;   // kk=0 granule
    const int rs1 = ((4 + quad) ^ (l15 & 7)) << 4;   // kk=1 granule
    const int arow = (wr * 128 + l15) * 128;         // + mi*8192 + f*2048
    const int brow = 32768 + (wc * 64 + l15) * 128;  // + ni*4096 + n*2048

    floatx4 acc[8][4];
    #pragma unroll
    for (int m = 0; m < 8; m++)
        #pragma unroll
        for (int n = 0; n < 4; n++)
            acc[m][n] = floatx4{0.f, 0.f, 0.f, 0.f};

    const int NT = K >> 6;          // K % 64 == 0 (K = 4096 here)

    // prologue: tile 0 complete (8 loads) + tile 1 first 3 halves (6 loads)
    stA0(0); stB0(0); stB1(0); stA1(0);
    if (NT > 1) {
        stA0(1); stB0(1); stB1(1);
        asm volatile("s_waitcnt vmcnt(6)\n\ts_barrier" ::: "memory");
    } else {
        asm volatile("s_waitcnt vmcnt(0)\n\ts_barrier" ::: "memory");
    }

    for (int t = 0; t < NT; ++t) {
        const uint8_t* buf = lds + (t & 1) * 65536;
        bf16x8 a[4][2], a2[4][2], b0[2][2], b1[2][2];

        // ---------------- p0: quadrant (m0,n0) ----------------
        if (t + 1 < NT) stA1(t + 1);
        #pragma unroll
        for (int f = 0; f < 4; f++) {
            a[f][0] = *(const bf16x8*)(buf + arow + f * 2048 + rs0);
            a[f][1] = *(const bf16x8*)(buf + arow + f * 2048 + rs1);
        }
        #pragma unroll
        for (int n = 0; n < 2; n++) {
            b0[n][0] = *(const bf16x8*)(buf + brow + n * 2048 + rs0);
            b0[n][1] = *(const bf16x8*)(buf + brow + n * 2048 + rs1);
        }
        asm volatile("s_waitcnt lgkmcnt(8)" ::: "memory");
        asm volatile("s_barrier" ::: "memory");
        asm volatile("s_waitcnt lgkmcnt(0)" ::: "memory");
        __builtin_amdgcn_s_setprio(1);
        #pragma unroll
        for (int f = 0; f < 4; f++)
            #pragma unroll
            for (int n = 0; n < 2; n++)
                #pragma unroll
                for (int kk = 0; kk < 2; kk++)
                    acc[f][n] = __builtin_amdgcn_mfma_f32_16x16x32_bf16(a[f][kk], b0[n][kk], acc[f][n], 0, 0, 0);
        __builtin_amdgcn_s_setprio(0);
        asm volatile("s_barrier" ::: "memory");

        // ---------------- p1: quadrant (m0,n1) ----------------
        if (t + 2 < NT) stA0(t + 2);
        #pragma unroll
        for (int n = 0; n < 2; n++) {
            b1[n][0] = *(const bf16x8*)(buf + brow + 4096 + n * 2048 + rs0);
            b1[n][1] = *(const bf16x8*)(buf + brow + 4096 + n * 2048 + rs1);
        }
        asm volatile("s_barrier" ::: "memory");
        asm volatile("s_waitcnt lgkmcnt(0)" ::: "memory");
        __builtin_amdgcn_s_setprio(1);
        #pragma unroll
        for (int f = 0; f < 4; f++)
            #pragma unroll
            for (int n = 0; n < 2; n++)
                #pragma unroll
                for (int kk = 0; kk < 2; kk++)
                    acc[f][2 + n] = __builtin_amdgcn_mfma_f32_16x16x32_bf16(a[f][kk], b1[n][kk], acc[f][2 + n], 0, 0, 0);
        __builtin_amdgcn_s_setprio(0);
        asm volatile("s_barrier" ::: "memory");

        // ---------------- p2: quadrant (m1,n1) ----------------
        if (t + 2 < NT) stB0(t + 2);
        #pragma unroll
        for (int f = 0; f < 4; f++) {
            a2[f][0] = *(const bf16x8*)(buf + arow + 8192 + f * 2048 + rs0);
            a2[f][1] = *(const bf16x8*)(buf + arow + 8192 + f * 2048 + rs1);
        }
        asm volatile("s_barrier" ::: "memory");
        asm volatile("s_waitcnt lgkmcnt(0)" ::: "memory");
        __builtin_amdgcn_s_setprio(1);
        #pragma unroll
        for (int f = 0; f < 4; f++)
            #pragma unroll
            for (int n = 0; n < 2; n++)
                #pragma unroll
                for (int kk = 0; kk < 2; kk++)
                    acc[4 + f][2 + n] = __builtin_amdgcn_mfma_f32_16x16x32_bf16(a2[f][kk], b1[n][kk], acc[4 + f][2 + n], 0, 0, 0);
        __builtin_amdgcn_s_setprio(0);
        asm volatile("s_barrier" ::: "memory");

        // ---------------- p3: quadrant (m1,n0), GATE ----------------
        if (t + 2 < NT) {
            stB1(t + 2);
            asm volatile("s_waitcnt vmcnt(6)\n\ts_barrier" ::: "memory");
        } else if (t + 1 < NT) {
            asm volatile("s_waitcnt vmcnt(0)\n\ts_barrier" ::: "memory");
        } else {
            asm volatile("s_barrier" ::: "memory");
        }
        __builtin_amdgcn_s_setprio(1);
        #pragma unroll
        for (int f = 0; f < 4; f++)
            #pragma unroll
            for (int n = 0; n < 2; n++)
                #pragma unroll
                for (int kk = 0; kk < 2; kk++)
                    acc[4 + f][n] = __builtin_amdgcn_mfma_f32_16x16x32_bf16(a2[f][kk], b0[n][kk], acc[4 + f][n], 0, 0, 0);
        __builtin_amdgcn_s_setprio(0);
        asm volatile("s_barrier" ::: "memory");
    }

    // epilogue: D row = quad*4 + reg (A side), col = l15 (B side) — m89/m91
    const int rowBase = bm + wr * 128 + quad * 4;
    const int colBase = bn + wc * 64 + l15;
    if (out_is_bf16) {
        unsigned short* C = (unsigned short*)Cout;
        #pragma unroll
        for (int m = 0; m < 8; m++)
            #pragma unroll
            for (int n = 0; n < 4; n++)
                #pragma unroll
                for (int r = 0; r < 4; r++)
                    C[(size_t)(rowBase + m * 16 + r) * N + colBase + n * 16] = f2bf(acc[m][n][r]);
    } else {
        float* C = (float*)Cout;
        #pragma unroll
        for (int m = 0; m < 8; m++)
            #pragma unroll
            for (int n = 0; n < 4; n++)
                #pragma unroll
                for (int r = 0; r < 4; r++)
                    C[(size_t)(rowBase + m * 16 + r) * N + colBase + n * 16] = acc[m][n][r];
    }
}

// ---------------- RoPE in-place on bf16 [*, nh, 128] -----------------------
__global__ void rope_kernel(unsigned short* __restrict__ t,
                            const float* __restrict__ fc,
                            const float* __restrict__ fs,
                            int nh, int total_pairs) {
    int idx = blockIdx.x * blockDim.x + threadIdx.x;
    if (idx >= total_pairs) return;
    int j   = idx & 63;            // HD/2 = 64
    int tmp = idx >> 6;            // (b*S + s)*nh + h
    int s   = (tmp / nh) & 1023;   // S = 1024
    float c  = fc[s * 64 + j];
    float sn = fs[s * 64 + j];
    size_t base = (size_t)tmp * 128 + j * 2;
    float tr = bf2f(t[base]), ti = bf2f(t[base + 1]);
    t[base]     = f2bf(tr * c - ti * sn);
    t[base + 1] = f2bf(tr * sn + ti * c);
}

// ---------------- flash attention (causal, GQA rep=4) ----------------------
#define AS_  1024
#define AHD 128
#define ANH 32
#define ANKV 8

__global__ __launch_bounds__(512, 4)
void attn_kernel(const unsigned short* __restrict__ Q,   // [B,S,NH,HD] bf16
                 const unsigned short* __restrict__ Kk,  // [B,S,NKV,HD]
                 const unsigned short* __restrict__ Vt,  // [NKV*HD][B*S]  (pre-transposed)
                 unsigned short* __restrict__ O)         // [B,S,NH,HD]
{
    __shared__ uint8_t lds[81920];   // [0,32K) K dbuf, [32K,64K) V dbuf, [64K,80K) P

    const int tid  = threadIdx.x;
    const int lane = tid & 63;
    const int wave = tid >> 6;      // 0..7
    const int quad = lane >> 4;
    const int l15  = lane & 15;

    const int bid = blockIdx.x;
    const int qt2 = 7 - (bid & 7);     // heavy q-tiles first
    const int h   = (bid >> 3) & 31;
    const int b   = bid >> 8;
    const int hk  = h >> 2;            // rep = NH/NKV = 4
    const int q0  = qt2 * 128;

    uint8_t* ldsK = lds;
    uint8_t* ldsV = lds + 32768;
    uint8_t* Ps   = lds + 65536 + wave * 2048;   // per-wave [16][64] swizzled

    const int krow0 = (2 * wave + 0) * 4 + (lane >> 4);
    const int krow1 = (2 * wave + 1) * 4 + (lane >> 4);
    const int kg0 = ((lane & 15) ^ (0 + (lane >> 4))) * 8;   // elem offset in row
    const int kg1 = ((lane & 15) ^ (4 + (lane >> 4))) * 8;
    const unsigned short* Kg0 = Kk + ((size_t)(b * AS_ + krow0) * ANKV + hk) * AHD + kg0;
    const unsigned short* Kg1 = Kk + ((size_t)(b * AS_ + krow1) * ANKV + hk) * AHD + kg1;
    const int vrow0 = (2 * wave + 0) * 8 + (lane >> 3);
    const int vrow1 = (2 * wave + 1) * 8 + (lane >> 3);
    const int vg = ((lane & 7) ^ (lane >> 3)) * 8;
    const unsigned short* Vg0 = Vt + (size_t)(hk * AHD + vrow0) * (4 * AS_) + b * AS_ + vg;
    const unsigned short* Vg1 = Vt + (size_t)(hk * AHD + vrow1) * (4 * AS_) + b * AS_ + vg;

    auto stage = [&](int t) {
        uint8_t* kb_ = ldsK + (t & 1) * 16384;
        uint8_t* vb_ = ldsV + (t & 1) * 16384;
        async_copy16(Kg0 + (size_t)t * 65536, kb_ + (2 * wave + 0) * 1024);
        async_copy16(Kg1 + (size_t)t * 65536, kb_ + (2 * wave + 1) * 1024);
        async_copy16(Vg0 + t * 64, vb_ + (2 * wave + 0) * 1024);
        async_copy16(Vg1 + t * 64, vb_ + (2 * wave + 1) * 1024);
    };

    bf16x8 aq[4];
    {
        const int qrow = q0 + wave * 16 + l15;
        const unsigned short* src = Q + ((size_t)(b * AS_ + qrow) * ANH + h) * AHD;
        #pragma unroll
        for (int kk = 0; kk < 4; kk++)
            aq[kk] = *(const bf16x8*)(src + kk * 32 + quad * 8);
    }

    float lsum[4];
    #pragma unroll
    for (int r = 0; r < 4; r++) lsum[r] = 0.0f;
    floatx4 o[8];
    #pragma unroll
    for (int d = 0; d < 8; d++) o[d] = floatx4{0.f, 0.f, 0.f, 0.f};

    const float scale = 0.08838834764831845f;  // 1/sqrt(128)
    const int wMaxKt = (q0 + wave * 16 + 15) >> 6;  // last tile this wave needs
    const int ktMax  = (q0 + 127) >> 6;             // = 2*qt2 + 1

    stage(0);
    const int swz = (l15 & 7) << 4;   // read-side XOR swizzle term

    for (int kt = 0; kt <= ktMax; ++kt) {
        if (kt < ktMax) {
            stage(kt + 1);   // safe: trailing barrier of iter kt-1 passed
            asm volatile("s_waitcnt vmcnt(4)\n\ts_barrier" ::: "memory");
        } else {
            asm volatile("s_waitcnt vmcnt(0)\n\ts_barrier" ::: "memory");
        }

        if (kt <= wMaxKt) {
            const uint8_t* kb_ = ldsK + (kt & 1) * 16384;
            const uint8_t* vb_ = ldsV + (kt & 1) * 16384;

            floatx4 sc[4];
            #pragma unroll
            for (int j = 0; j < 4; j++) sc[j] = floatx4{0.f, 0.f, 0.f, 0.f};
            __builtin_amdgcn_s_setprio(1);
            #pragma unroll
            for (int j = 0; j < 4; j++)
                #pragma unroll
                for (int kk = 0; kk < 4; kk++) {
                    bf16x8 bk = *(const bf16x8*)(kb_ + (j * 16 + l15) * 256 +
                                  (((kk * 4 + quad) << 4) ^ swz));
                    sc[j] = __builtin_amdgcn_mfma_f32_16x16x32_bf16(aq[kk], bk, sc[j], 0, 0, 0);
                }
            __builtin_amdgcn_s_setprio(0);

            #pragma unroll
            for (int r = 0; r < 4; r++) {
                const int row  = quad * 4 + r;
                const int qrow = q0 + wave * 16 + row;
                const bool needMask = (kt * 64 + 63 > qrow);
                float acc = 0.0f;
                #pragma unroll
                for (int j = 0; j < 4; j++) {
                    float e = __expf(sc[j][r] * scale);
                    if (needMask) {
                        int key = kt * 64 + j * 16 + l15;
                        if (key > qrow) e = 0.0f;   // causal
                    }
                    acc += e;
                    int g = (j * 2 + (l15 >> 3)) ^ (row & 7);
                    *(unsigned short*)(Ps + row * 128 + (g << 4) + (l15 & 7) * 2) = f2bf(e);
                }
                lsum[r] += acc;
            }

            __builtin_amdgcn_s_setprio(1);
            #pragma unroll
            for (int kk = 0; kk < 2; kk++) {
                bf16x8 ap = *(const bf16x8*)(Ps + l15 * 128 +
                              (((kk * 4 + quad) << 4) ^ swz));
                #pragma unroll
                for (int d = 0; d < 8; d++) {
                    bf16x8 bv = *(const bf16x8*)(vb_ + (d * 16 + l15) * 128 +
                                  (((kk * 4 + quad) << 4) ^ swz));
                    o[d] = __builtin_amdgcn_mfma_f32_16x16x32_bf16(ap, bv, o[d], 0, 0, 0);
                }
            }
            __builtin_amdgcn_s_setprio(0);
        }

        asm volatile("s_barrier" ::: "memory");
    }

    #pragma unroll
    for (int r = 0; r < 4; r++) {
        float s = lsum[r];
        #pragma unroll
        for (int off = 1; off < 16; off <<= 1)
            s += __shfl_xor(s, off, 64);
        float inv = 1.0f / s;
        int qrow = q0 + wave * 16 + quad * 4 + r;
        unsigned short* dst = O + ((size_t)(b * AS_ + qrow) * ANH + h) * AHD;
        #pragma unroll
        for (int d = 0; d < 8; d++)
            dst[d * 16 + l15] = f2bf(o[d][r] * inv);
    }
}

// ---------------------------------------------------------------------------
extern "C" void kernel_launch(void* const* d_in, const int* in_sizes, int n_in,
                              void* d_out, int out_size, void* d_ws, size_t ws_size,
                              hipStream_t stream)
{
    const float* x  = (const float*)d_in[0];
    const float* wq = (const float*)d_in[1];
    const float* wk = (const float*)d_in[2];
    const float* wv = (const float*)d_in[3];
    const float* wo = (const float*)d_in[4];
    const float* fc = (const float*)d_in[5];
    const float* fs = (const float*)d_in[6];

    const int B = 4, S = 1024, D = 4096, NH = 32, NKV = 8, HD = 128;
    const int M    = B * S;       // 4096 tokens
    const int NQ   = NH * HD;     // 4096
    const int NKVD = NKV * HD;    // 1024

    unsigned short* ws = (unsigned short*)d_ws;
    size_t off = 0;
    unsigned short* xb  = ws + off; off += (size_t)M * D;      // 32 MiB
    unsigned short* wqb = ws + off; off += (size_t)NQ * D;     // 32 MiB
    unsigned short* wkb = ws + off; off += (size_t)NKVD * D;   //  8 MiB
    unsigned short* wvb = ws + off; off += (size_t)NKVD * D;   //  8 MiB
    unsigned short* wob = ws + off; off += (size_t)D * NQ;     // 32 MiB
    unsigned short* qb  = ws + off; off += (size_t)M * NQ;     // 32 MiB
    unsigned short* kb  = ws + off; off += (size_t)M * NKVD;   //  8 MiB
    unsigned short* vtb = ws + off; off += (size_t)NKVD * M;   //  8 MiB (V^T)
    unsigned short* aob = ws + off; off += (size_t)M * NQ;     // 32 MiB

    // 1) casts fp32 -> bf16
    {
        struct { const float* src; unsigned short* dst; size_t n; } jobs[5] = {
            { x,  xb,  (size_t)M * D },
            { wq, wqb, (size_t)NQ * D },
            { wk, wkb, (size_t)NKVD * D },
            { wv, wvb, (size_t)NKVD * D },
            { wo, wob, (size_t)D * NQ },
        };
        for (int i = 0; i < 5; i++) {
            int n4 = (int)(jobs[i].n / 4);
            cast_bf16_kernel<<<(n4 + 255) / 256, 256, 0, stream>>>(jobs[i].src, jobs[i].dst, n4);
        }
    }

    // 2) projections
    gemm_bt_256_kernel<<<dim3(NQ / 256,  M / 256), 512, 0, stream>>>(xb,  wqb, qb,  M,   NQ, D, 1);
    gemm_bt_kernel<<<dim3(NKVD / GBN, M / GBM), 256, 0, stream>>>(xb,  wkb, kb,  M, NKVD, D, 1);
    gemm_bt_kernel<<<dim3(M / GBN, NKVD / GBM), 256, 0, stream>>>(wvb, xb,  vtb, NKVD, M, D, 1);

    // 3) RoPE in-place on Q and K (not V)
    {
        int pq = M * NH * (HD / 2);
        rope_kernel<<<(pq + 255) / 256, 256, 0, stream>>>(qb, fc, fs, NH, pq);
        int pk = M * NKV * (HD / 2);
        rope_kernel<<<(pk + 255) / 256, 256, 0, stream>>>(kb, fc, fs, NKV, pk);
    }

    // 4) flash attention -> aob (bf16): 128 q-rows per block, 512 threads
    attn_kernel<<<B * NH * (S / 128), 512, 0, stream>>>(qb, kb, vtb, aob);

    // 5) output projection (fp32 out to d_out)
    gemm_bt_256_kernel<<<dim3(D / 256, M / 256), 512, 0, stream>>>(aob, wob, d_out, M, D, NQ, 0);
}